// Round 10
// baseline (525.478 us; speedup 1.0000x reference)
//
#include <hip/hip_runtime.h>
#include <hip/hip_bf16.h>
#include <hip/hip_fp16.h>

// ---------------------------------------------------------------------------
// GAT 3-layer forward, round 10 = round-9 (passing) + latency-batched gather
// in the aggregation kernels (8 edges in flight per lane; SS/SX padded so the
// batch needs no per-load guards).
// ---------------------------------------------------------------------------

#define HEADS 8
#define F512 512

typedef __bf16 bf16x8 __attribute__((ext_vector_type(8)));
typedef unsigned short u16x8 __attribute__((ext_vector_type(8)));
typedef float f32x4 __attribute__((ext_vector_type(4)));

__device__ __forceinline__ unsigned bf16_rne(float f) {
    unsigned u = __float_as_uint(f);
    return (u + 0x7FFFu + ((u >> 16) & 1u)) >> 16;
}

#if defined(__has_builtin)
#if __has_builtin(__builtin_amdgcn_global_load_lds)
#define HAS_GLL 1
#endif
#endif

__device__ __forceinline__ void gll16(const void* g, void* l) {
#ifdef HAS_GLL
    __builtin_amdgcn_global_load_lds(
        (const __attribute__((address_space(1))) unsigned int*)g,
        (__attribute__((address_space(3))) unsigned int*)l, 16, 0, 0);
#else
    *(uint4*)l = *(const uint4*)g;
#endif
}

// ---------------- Layer-1 GEMM + alpha, wave per node ----------------
__global__ __launch_bounds__(256) void gemm1_fused(
    const float* __restrict__ x, const float* __restrict__ W1,
    const float* __restrict__ asrc, const float* __restrict__ adst,
    __half* __restrict__ h16, float* __restrict__ a_s, float* __restrict__ a_d,
    int N) {
    int w = (blockIdx.x * blockDim.x + threadIdx.x) >> 6;
    int l = threadIdx.x & 63;
    if (w >= N) return;
    const float* xr = x + (size_t)w * 12;
    float4 xa = *(const float4*)(xr);
    float4 xb = *(const float4*)(xr + 4);
    float4 xc = *(const float4*)(xr + 8);
    float xv[12] = {xa.x, xa.y, xa.z, xa.w, xb.x, xb.y, xb.z, xb.w, xc.x, xc.y, xc.z, xc.w};
    int c0 = l * 8;
    float o[8] = {};
#pragma unroll
    for (int k = 0; k < 12; ++k) {
        const float4* wr = (const float4*)(W1 + k * F512 + c0);
        float4 w0 = wr[0], w1 = wr[1];
        o[0] += xv[k] * w0.x; o[1] += xv[k] * w0.y; o[2] += xv[k] * w0.z; o[3] += xv[k] * w0.w;
        o[4] += xv[k] * w1.x; o[5] += xv[k] * w1.y; o[6] += xv[k] * w1.z; o[7] += xv[k] * w1.w;
    }
    __half hv[8];
#pragma unroll
    for (int k = 0; k < 8; ++k) hv[k] = __float2half_rn(o[k]);
    *(uint4*)(h16 + (size_t)w * F512 + c0) = *(uint4*)hv;
    float s = 0.f, d = 0.f;
#pragma unroll
    for (int k = 0; k < 8; ++k) { s += o[k] * asrc[c0 + k]; d += o[k] * adst[c0 + k]; }
    s += __shfl_xor(s, 1); d += __shfl_xor(d, 1);
    s += __shfl_xor(s, 2); d += __shfl_xor(d, 2);
    s += __shfl_xor(s, 4); d += __shfl_xor(d, 4);
    if ((l & 7) == 0) { a_s[w * 8 + (l >> 3)] = s; a_d[w * 8 + (l >> 3)] = d; }
}

// W2 [K=512][N=512] -> chunk-swizzled bf16 hi/lo planes, n-major [n][k]
__global__ void convW2p(const float* __restrict__ W2, unsigned short* __restrict__ BTH,
                        unsigned short* __restrict__ BTL) {
    int t = blockIdx.x * blockDim.x + threadIdx.x;
    if (t >= F512 * 64) return;
    int n = t >> 6, c = t & 63;
    int g = c >> 2, cc = c & 3;
    int st = g * 32 + ((cc ^ ((n >> 1) & 3)) << 3);
    unsigned short hs[8], ls[8];
#pragma unroll
    for (int j = 0; j < 8; ++j) {
        float f = W2[(size_t)(c * 8 + j) * F512 + n];
        unsigned hi = bf16_rne(f);
        float r = f - __uint_as_float(hi << 16);
        hs[j] = (unsigned short)hi;
        ls[j] = (unsigned short)bf16_rne(r);
    }
    *(uint4*)&BTH[(size_t)n * F512 + st] = *(uint4*)hs;
    *(uint4*)&BTL[(size_t)n * F512 + st] = *(uint4*)ls;
}

// ---------------- CSR build ----------------

__global__ void hist_kernel(const int* __restrict__ dst, int E, int* __restrict__ cnt) {
    int e = blockIdx.x * blockDim.x + threadIdx.x;
    if (e < E) atomicAdd(&cnt[dst[e]], 1);
}

__global__ __launch_bounds__(1024) void scan_block_kernel(const int* __restrict__ cnt,
                                                          int* __restrict__ excl,
                                                          int* __restrict__ bsum, int n) {
    __shared__ int s[1024];
    int i = blockIdx.x * 1024 + threadIdx.x;
    int v = i < n ? cnt[i] : 0;
    s[threadIdx.x] = v;
    __syncthreads();
    for (int off = 1; off < 1024; off <<= 1) {
        int t = threadIdx.x >= off ? s[threadIdx.x - off] : 0;
        __syncthreads();
        s[threadIdx.x] += t;
        __syncthreads();
    }
    if (i < n) excl[i] = s[threadIdx.x] - v;
    if (threadIdx.x == 1023) bsum[blockIdx.x] = s[1023];
}

__global__ void scan_aux_kernel(int* __restrict__ bsum, int nb) {
    if (blockIdx.x == 0 && threadIdx.x == 0) {
        int acc = 0;
        for (int i = 0; i < nb; ++i) { int v = bsum[i]; bsum[i] = acc; acc += v; }
    }
}

__global__ void scan_add_kernel(const int* __restrict__ excl, const int* __restrict__ bsum,
                                int* __restrict__ rowptr, int* __restrict__ fill, int n, int E) {
    int i = blockIdx.x * blockDim.x + threadIdx.x;
    if (i < n) {
        int v = excl[i] + bsum[i >> 10];
        rowptr[i] = v;
        fill[i] = v;
    }
    if (i == 0) rowptr[n] = E;
}

__global__ void scatter_kernel(const int* __restrict__ src, const int* __restrict__ dst, int E,
                               int* __restrict__ fill, int* __restrict__ csrc) {
    int e = blockIdx.x * blockDim.x + threadIdx.x;
    if (e >= E) return;
    int pos = atomicAdd(&fill[dst[e]], 1);
    csrc[pos] = src[e];
}

// ---------------- wave-per-dst fused softmax + aggregation ----------------
// Batched gather: 8 edges in flight per lane. SS fully initialized (dummy=d),
// SX tail zero-filled, so the 8-load batch needs no guards.
// MODE 0: bias+ELU -> hi/lo bf16 planes, chunk-swizzled (feeds gemm2)
// MODE 1: bias+ELU -> h3 = h2@W3, as3/ad3 (h2 not stored)

template <int MODE>
__global__ __launch_bounds__(256) void gat_aggr_wave(
    const int* __restrict__ rowptr, const int* __restrict__ csrc,
    const float* __restrict__ a_s, const float* __restrict__ a_d,
    const __half* __restrict__ h16, const float* __restrict__ bias,
    unsigned short* __restrict__ aggH, unsigned short* __restrict__ aggL,
    const float* __restrict__ W3, const float* __restrict__ asrc3,
    const float* __restrict__ adst3, float* __restrict__ h3,
    float* __restrict__ as3, float* __restrict__ ad3, int N) {
    __shared__ float sexs[4][64 * 8];
    __shared__ int ssrcs[4][64];
    int wv = threadIdx.x >> 6, l = threadIdx.x & 63;
    int d = blockIdx.x * 4 + wv;
    if (d >= N) return;
    float* SX = sexs[wv];
    int* SS = ssrcs[wv];
    int beg = rowptr[d], deg = rowptr[d + 1] - beg;
    int hq = l & 7, hmy = l >> 3;
    float adq = a_d[d * 8 + hq];

    // pass 1: per-head max over all edges (+self)
    float m = -INFINITY;
    for (int i = l >> 3; i <= deg; i += 8) {
        int s = (i == deg) ? d : csrc[beg + i];
        float v = a_s[s * 8 + hq] + adq;
        v = v >= 0.f ? v : 0.2f * v;
        m = fmaxf(m, v);
    }
    m = fmaxf(m, __shfl_xor(m, 8));
    m = fmaxf(m, __shfl_xor(m, 16));
    m = fmaxf(m, __shfl_xor(m, 32));

    // pass 2 (chunked): exp -> LDS, denom partials, batched feature gather
    float den = 0.f;
    float acc[8] = {};
    for (int c0 = 0; c0 <= deg; c0 += 64) {
        int cnt = min(64, deg + 1 - c0);
        {
            int i = c0 + l;
            SS[l] = (i < deg) ? csrc[beg + i] : d;   // i==deg -> self; i>deg -> dummy self
        }
        __builtin_amdgcn_wave_barrier();
        for (int i = l >> 3; i < 64; i += 8) {
            float ex = 0.f;
            if (i < cnt) {
                int s = SS[i];
                float v = a_s[s * 8 + hq] + adq;
                v = v >= 0.f ? v : 0.2f * v;
                ex = __expf(v - m);
                den += ex;
            }
            SX[i * 8 + hq] = ex;
        }
        __builtin_amdgcn_wave_barrier();
        for (int j0 = 0; j0 < cnt; j0 += 8) {
            int ssr[8]; float eer[8]; uint4 hv[8];
#pragma unroll
            for (int t = 0; t < 8; ++t) {
                ssr[t] = SS[j0 + t];
                eer[t] = SX[(j0 + t) * 8 + hmy];
            }
#pragma unroll
            for (int t = 0; t < 8; ++t)
                hv[t] = *(const uint4*)(h16 + (size_t)ssr[t] * F512 + l * 8);
#pragma unroll
            for (int t = 0; t < 8; ++t) {
                const __half2* hp = (const __half2*)&hv[t];
                float ex = eer[t];
#pragma unroll
                for (int k = 0; k < 4; ++k) {
                    float2 f = __half22float2(hp[k]);
                    acc[2 * k] += ex * f.x;
                    acc[2 * k + 1] += ex * f.y;
                }
            }
        }
        __builtin_amdgcn_wave_barrier();
    }
    den += __shfl_xor(den, 8);
    den += __shfl_xor(den, 16);
    den += __shfl_xor(den, 32);
    float dg = __shfl(den, hmy);
    float inv = 1.f / (dg + 1e-16f);

    int c0c = l * 8;
    float o[8];
#pragma unroll
    for (int k = 0; k < 8; ++k) {
        float t = acc[k] * inv + bias[c0c + k];
        o[k] = t > 0.f ? t : expm1f(t);
    }

    if (MODE == 0) {
        unsigned short hs[8], ls[8];
#pragma unroll
        for (int k = 0; k < 8; ++k) {
            unsigned hi = bf16_rne(o[k]);
            float r = o[k] - __uint_as_float(hi << 16);
            hs[k] = (unsigned short)hi;
            ls[k] = (unsigned short)bf16_rne(r);
        }
        int st = (l >> 2) * 32 + (((l & 3) ^ ((d >> 1) & 3)) << 3);
        *(uint4*)&aggH[(size_t)d * F512 + st] = *(uint4*)hs;
        *(uint4*)&aggL[(size_t)d * F512 + st] = *(uint4*)ls;
    } else {
        float p0 = 0.f, p1 = 0.f, p2 = 0.f;
#pragma unroll
        for (int k = 0; k < 8; ++k) {
            float t = o[k];
            p0 += t * W3[(c0c + k) * 3 + 0];
            p1 += t * W3[(c0c + k) * 3 + 1];
            p2 += t * W3[(c0c + k) * 3 + 2];
        }
#pragma unroll
        for (int off = 1; off < 64; off <<= 1) {
            p0 += __shfl_xor(p0, off);
            p1 += __shfl_xor(p1, off);
            p2 += __shfl_xor(p2, off);
        }
        if (l == 0) {
            h3[(size_t)d * 3 + 0] = p0;
            h3[(size_t)d * 3 + 1] = p1;
            h3[(size_t)d * 3 + 2] = p2;
            as3[d] = p0 * asrc3[0] + p1 * asrc3[1] + p2 * asrc3[2];
            ad3[d] = p0 * adst3[0] + p1 * adst3[1] + p2 * adst3[2];
        }
    }
}

// ---------------- Layer-2 GEMM: hi/lo planes + global_load_lds + fused alpha ----------------
__global__ __launch_bounds__(256) void gemm2_gll(
    const unsigned short* __restrict__ AH, const unsigned short* __restrict__ AL,
    const unsigned short* __restrict__ BH, const unsigned short* __restrict__ BL,
    const float* __restrict__ asrc2, const float* __restrict__ adst2,
    __half* __restrict__ C, float* __restrict__ a_s, float* __restrict__ a_d,
    int M) {
    __shared__ unsigned short AsH[128 * 32], AsL[128 * 32];
    __shared__ unsigned short BsH[128 * 32], BsL[128 * 32];

    int nwg = gridDim.x, o = blockIdx.x;
    int q = nwg >> 3, r = nwg & 7, xcd = o & 7;
    int base = xcd < r ? xcd * (q + 1) : r * (q + 1) + (xcd - r) * q;
    int lg = base + (o >> 3);
    int mb = lg >> 2, nb = lg & 3;

    int tid = threadIdx.x, lane = tid & 63, wv = tid >> 6;
    int wm = wv >> 1, wn = wv & 1;
    int seg = lane >> 4;
    int srow = tid >> 2, sch = tid & 3;

    f32x4 acc[4][4] = {};

    for (int k0 = 0; k0 < F512; k0 += 32) {
#pragma unroll
        for (int u = 0; u < 2; ++u) {
            size_t ga = (size_t)(mb * 128 + srow + u * 64) * F512 + k0 + sch * 8;
            size_t gb = (size_t)(nb * 128 + srow + u * 64) * F512 + k0 + sch * 8;
            int ldst = wv * 512 + u * 2048;
            gll16(AH + ga, &AsH[ldst]);
            gll16(AL + ga, &AsL[ldst]);
            gll16(BH + gb, &BsH[ldst]);
            gll16(BL + gb, &BsL[ldst]);
        }
        __syncthreads();

        bf16x8 aH[4], aL[4], bH[4], bL[4];
#pragma unroll
        for (int mi = 0; mi < 4; ++mi) {
            int arow = wm * 64 + mi * 16 + (lane & 15);
            int aoff = arow * 32 + ((seg ^ ((arow >> 1) & 3)) << 3);
            aH[mi] = __builtin_bit_cast(bf16x8, *(const u16x8*)&AsH[aoff]);
            aL[mi] = __builtin_bit_cast(bf16x8, *(const u16x8*)&AsL[aoff]);
        }
#pragma unroll
        for (int ni = 0; ni < 4; ++ni) {
            int brow = wn * 64 + ni * 16 + (lane & 15);
            int boff = brow * 32 + ((seg ^ ((brow >> 1) & 3)) << 3);
            bH[ni] = __builtin_bit_cast(bf16x8, *(const u16x8*)&BsH[boff]);
            bL[ni] = __builtin_bit_cast(bf16x8, *(const u16x8*)&BsL[boff]);
        }
#pragma unroll
        for (int mi = 0; mi < 4; ++mi)
#pragma unroll
            for (int ni = 0; ni < 4; ++ni) {
                acc[mi][ni] = __builtin_amdgcn_mfma_f32_16x16x32_bf16(aH[mi], bH[ni], acc[mi][ni], 0, 0, 0);
                acc[mi][ni] = __builtin_amdgcn_mfma_f32_16x16x32_bf16(aH[mi], bL[ni], acc[mi][ni], 0, 0, 0);
                acc[mi][ni] = __builtin_amdgcn_mfma_f32_16x16x32_bf16(aL[mi], bH[ni], acc[mi][ni], 0, 0, 0);
            }
        __syncthreads();
    }

    // C (fp16 h2pre) write
#pragma unroll
    for (int mi = 0; mi < 4; ++mi) {
#pragma unroll
        for (int ni = 0; ni < 4; ++ni) {
            int rbase = mb * 128 + wm * 64 + mi * 16 + (lane >> 4) * 4;
            int c = nb * 128 + wn * 64 + ni * 16 + (lane & 15);
#pragma unroll
            for (int i = 0; i < 4; ++i) {
                int row = rbase + i;
                if (row < M) C[(size_t)row * F512 + c] = __float2half_rn(acc[mi][ni][i]);
            }
        }
    }

    // fused alpha: this wave's 64 cols == head (nb*2+wn)
    int head = nb * 2 + wn;
    float av[4], dv[4];
#pragma unroll
    for (int ni = 0; ni < 4; ++ni) {
        int cw = ni * 16 + (lane & 15);
        av[ni] = asrc2[head * 64 + cw];
        dv[ni] = adst2[head * 64 + cw];
    }
#pragma unroll
    for (int mi = 0; mi < 4; ++mi)
#pragma unroll
        for (int i = 0; i < 4; ++i) {
            float sp = 0.f, dp = 0.f;
#pragma unroll
            for (int ni = 0; ni < 4; ++ni) {
                sp += acc[mi][ni][i] * av[ni];
                dp += acc[mi][ni][i] * dv[ni];
            }
            sp += __shfl_xor(sp, 1); dp += __shfl_xor(dp, 1);
            sp += __shfl_xor(sp, 2); dp += __shfl_xor(dp, 2);
            sp += __shfl_xor(sp, 4); dp += __shfl_xor(dp, 4);
            sp += __shfl_xor(sp, 8); dp += __shfl_xor(dp, 8);
            if ((lane & 15) == 0) {
                int row = mb * 128 + wm * 64 + mi * 16 + (lane >> 4) * 4 + i;
                if (row < M) { a_s[row * 8 + head] = sp; a_d[row * 8 + head] = dp; }
            }
        }
}

// ---------------- layer-3 aggregation ----------------
__global__ __launch_bounds__(256) void gat_aggr3_fused(
    const int* __restrict__ rowptr, const int* __restrict__ csrc,
    const float* __restrict__ a_s, const float* __restrict__ a_d,
    const float* __restrict__ h3, const float* __restrict__ b3,
    float* __restrict__ out, int N) {
    int w = (blockIdx.x * blockDim.x + threadIdx.x) >> 6;
    int lane = threadIdx.x & 63;
    if (w >= N) return;
    int d = w;
    int beg = rowptr[d], deg = rowptr[d + 1] - beg;
    float ad = a_d[d];
    float m = -INFINITY;
    for (int i = lane; i <= deg; i += 64) {
        int s = (i == deg) ? d : csrc[beg + i];
        float v = a_s[s] + ad;
        v = v >= 0.f ? v : 0.2f * v;
        m = fmaxf(m, v);
    }
    for (int off = 32; off; off >>= 1) m = fmaxf(m, __shfl_xor(m, off));
    float den = 0.f, c0 = 0.f, c1 = 0.f, c2 = 0.f;
    for (int i = lane; i <= deg; i += 64) {
        int s = (i == deg) ? d : csrc[beg + i];
        float v = a_s[s] + ad;
        v = v >= 0.f ? v : 0.2f * v;
        float ex = __expf(v - m);
        den += ex;
        c0 += ex * h3[(size_t)s * 3 + 0];
        c1 += ex * h3[(size_t)s * 3 + 1];
        c2 += ex * h3[(size_t)s * 3 + 2];
    }
    for (int off = 32; off; off >>= 1) {
        den += __shfl_xor(den, off);
        c0 += __shfl_xor(c0, off);
        c1 += __shfl_xor(c1, off);
        c2 += __shfl_xor(c2, off);
    }
    if (lane == 0) {
        float inv = 1.f / (den + 1e-16f);
        out[(size_t)d * 3 + 0] = c0 * inv + b3[0];
        out[(size_t)d * 3 + 1] = c1 * inv + b3[1];
        out[(size_t)d * 3 + 2] = c2 * inv + b3[2];
    }
}

static inline int cdiv(long long a, long long b) { return (int)((a + b - 1) / b); }
static inline size_t rup(size_t v) { return (v + 255) & ~(size_t)255; }

extern "C" void kernel_launch(void* const* d_in, const int* in_sizes, int n_in,
                              void* d_out, int out_size, void* d_ws, size_t ws_size,
                              hipStream_t stream) {
    const int N = in_sizes[0] / 12;
    const int E = in_sizes[1] / 2;
    const float* x     = (const float*)d_in[0];
    const int*   ei    = (const int*)d_in[1];
    const float* W1    = (const float*)d_in[2];
    const float* asrc1 = (const float*)d_in[3];
    const float* adst1 = (const float*)d_in[4];
    const float* b1    = (const float*)d_in[5];
    const float* W2    = (const float*)d_in[6];
    const float* asrc2 = (const float*)d_in[7];
    const float* adst2 = (const float*)d_in[8];
    const float* b2    = (const float*)d_in[9];
    const float* W3    = (const float*)d_in[10];
    const float* asrc3 = (const float*)d_in[11];
    const float* adst3 = (const float*)d_in[12];
    const float* b3    = (const float*)d_in[13];

    const int* srcv = ei;
    const int* dstv = ei + E;
    float* out = (float*)d_out;

    const int Mpad = cdiv(N, 128) * 128;
    char* p = (char*)d_ws;
    __half*         h16  = (__half*)p;         p += rup((size_t)N * F512 * 2);
    unsigned short* aggH = (unsigned short*)p; p += rup((size_t)Mpad * F512 * 2);
    unsigned short* aggL = (unsigned short*)p; p += rup((size_t)Mpad * F512 * 2);
    float* a_s    = (float*)p;  p += rup((size_t)Mpad * HEADS * 4);
    float* a_d    = (float*)p;  p += rup((size_t)Mpad * HEADS * 4);
    float* h3     = (float*)p;  p += rup((size_t)N * 3 * 4);
    float* as3    = (float*)p;  p += rup((size_t)N * 4);
    float* ad3    = (float*)p;  p += rup((size_t)N * 4);
    int*   cnt    = (int*)p;    p += rup((size_t)N * 4);
    int*   excl   = (int*)p;    p += rup((size_t)N * 4);
    int*   rowptr = (int*)p;    p += rup((size_t)(N + 1) * 4);
    int*   fill   = (int*)p;    p += rup((size_t)N * 4);
    int*   bsum   = (int*)p;    p += rup(4096);
    int*   csrc   = (int*)p;    p += rup((size_t)E * 4);
    unsigned short* BTH = (unsigned short*)p; p += rup((size_t)F512 * F512 * 2);
    unsigned short* BTL = (unsigned short*)p; p += rup((size_t)F512 * F512 * 2);

    const int nb = cdiv(N, 1024);

    // ---- CSR build + W2 plane conversion ----
    hipMemsetAsync(cnt, 0, (size_t)N * 4, stream);
    hist_kernel<<<cdiv(E, 256), 256, 0, stream>>>(dstv, E, cnt);
    scan_block_kernel<<<nb, 1024, 0, stream>>>(cnt, excl, bsum, N);
    scan_aux_kernel<<<1, 64, 0, stream>>>(bsum, nb);
    scan_add_kernel<<<cdiv(N + 1, 256), 256, 0, stream>>>(excl, bsum, rowptr, fill, N, E);
    scatter_kernel<<<cdiv(E, 256), 256, 0, stream>>>(srcv, dstv, E, fill, csrc);
    convW2p<<<cdiv(F512 * 64, 256), 256, 0, stream>>>(W2, BTH, BTL);

    // ----------------- Layer 1 -----------------
    gemm1_fused<<<cdiv((long long)N * 64, 256), 256, 0, stream>>>(
        x, W1, asrc1, adst1, h16, a_s, a_d, N);
    gat_aggr_wave<0><<<cdiv(N, 4), 256, 0, stream>>>(
        rowptr, csrc, a_s, a_d, h16, b1, aggH, aggL,
        nullptr, nullptr, nullptr, nullptr, nullptr, nullptr, N);

    // ----------------- Layer 2 -----------------
    gemm2_gll<<<(Mpad / 128) * 4, 256, 0, stream>>>(
        aggH, aggL, BTH, BTL, asrc2, adst2, h16, a_s, a_d, N);
    gat_aggr_wave<1><<<cdiv(N, 4), 256, 0, stream>>>(
        rowptr, csrc, a_s, a_d, h16, b2, nullptr, nullptr,
        W3, asrc3, adst3, h3, as3, ad3, N);

    // ----------------- Layer 3 -----------------
    gat_aggr3_fused<<<cdiv((long long)N, 4), 256, 0, stream>>>(
        rowptr, csrc, as3, ad3, h3, b3, out, N);
}

// Round 11
// 501.662 us; speedup vs baseline: 1.0475x; 1.0475x over previous
//
#include <hip/hip_runtime.h>
#include <hip/hip_bf16.h>
#include <hip/hip_fp16.h>

// ---------------------------------------------------------------------------
// GAT 3-layer forward, round 11 = round-9 (passing, 502us) + 1-ahead rotating
// prefetch in the aggregation gather loop (VGPR kept under the 64-reg
// occupancy cliff that sank round 10).
// ---------------------------------------------------------------------------

#define HEADS 8
#define F512 512

typedef __bf16 bf16x8 __attribute__((ext_vector_type(8)));
typedef unsigned short u16x8 __attribute__((ext_vector_type(8)));
typedef float f32x4 __attribute__((ext_vector_type(4)));

__device__ __forceinline__ unsigned bf16_rne(float f) {
    unsigned u = __float_as_uint(f);
    return (u + 0x7FFFu + ((u >> 16) & 1u)) >> 16;
}

#if defined(__has_builtin)
#if __has_builtin(__builtin_amdgcn_global_load_lds)
#define HAS_GLL 1
#endif
#endif

__device__ __forceinline__ void gll16(const void* g, void* l) {
#ifdef HAS_GLL
    __builtin_amdgcn_global_load_lds(
        (const __attribute__((address_space(1))) unsigned int*)g,
        (__attribute__((address_space(3))) unsigned int*)l, 16, 0, 0);
#else
    *(uint4*)l = *(const uint4*)g;
#endif
}

// ---------------- Layer-1 GEMM + alpha, wave per node ----------------
__global__ __launch_bounds__(256) void gemm1_fused(
    const float* __restrict__ x, const float* __restrict__ W1,
    const float* __restrict__ asrc, const float* __restrict__ adst,
    __half* __restrict__ h16, float* __restrict__ a_s, float* __restrict__ a_d,
    int N) {
    int w = (blockIdx.x * blockDim.x + threadIdx.x) >> 6;
    int l = threadIdx.x & 63;
    if (w >= N) return;
    const float* xr = x + (size_t)w * 12;
    float4 xa = *(const float4*)(xr);
    float4 xb = *(const float4*)(xr + 4);
    float4 xc = *(const float4*)(xr + 8);
    float xv[12] = {xa.x, xa.y, xa.z, xa.w, xb.x, xb.y, xb.z, xb.w, xc.x, xc.y, xc.z, xc.w};
    int c0 = l * 8;
    float o[8] = {};
#pragma unroll
    for (int k = 0; k < 12; ++k) {
        const float4* wr = (const float4*)(W1 + k * F512 + c0);
        float4 w0 = wr[0], w1 = wr[1];
        o[0] += xv[k] * w0.x; o[1] += xv[k] * w0.y; o[2] += xv[k] * w0.z; o[3] += xv[k] * w0.w;
        o[4] += xv[k] * w1.x; o[5] += xv[k] * w1.y; o[6] += xv[k] * w1.z; o[7] += xv[k] * w1.w;
    }
    __half hv[8];
#pragma unroll
    for (int k = 0; k < 8; ++k) hv[k] = __float2half_rn(o[k]);
    *(uint4*)(h16 + (size_t)w * F512 + c0) = *(uint4*)hv;
    float s = 0.f, d = 0.f;
#pragma unroll
    for (int k = 0; k < 8; ++k) { s += o[k] * asrc[c0 + k]; d += o[k] * adst[c0 + k]; }
    s += __shfl_xor(s, 1); d += __shfl_xor(d, 1);
    s += __shfl_xor(s, 2); d += __shfl_xor(d, 2);
    s += __shfl_xor(s, 4); d += __shfl_xor(d, 4);
    if ((l & 7) == 0) { a_s[w * 8 + (l >> 3)] = s; a_d[w * 8 + (l >> 3)] = d; }
}

// W2 [K=512][N=512] -> chunk-swizzled bf16 hi/lo planes, n-major [n][k]
__global__ void convW2p(const float* __restrict__ W2, unsigned short* __restrict__ BTH,
                        unsigned short* __restrict__ BTL) {
    int t = blockIdx.x * blockDim.x + threadIdx.x;
    if (t >= F512 * 64) return;
    int n = t >> 6, c = t & 63;
    int g = c >> 2, cc = c & 3;
    int st = g * 32 + ((cc ^ ((n >> 1) & 3)) << 3);
    unsigned short hs[8], ls[8];
#pragma unroll
    for (int j = 0; j < 8; ++j) {
        float f = W2[(size_t)(c * 8 + j) * F512 + n];
        unsigned hi = bf16_rne(f);
        float r = f - __uint_as_float(hi << 16);
        hs[j] = (unsigned short)hi;
        ls[j] = (unsigned short)bf16_rne(r);
    }
    *(uint4*)&BTH[(size_t)n * F512 + st] = *(uint4*)hs;
    *(uint4*)&BTL[(size_t)n * F512 + st] = *(uint4*)ls;
}

// ---------------- CSR build ----------------

__global__ void hist_kernel(const int* __restrict__ dst, int E, int* __restrict__ cnt) {
    int e = blockIdx.x * blockDim.x + threadIdx.x;
    if (e < E) atomicAdd(&cnt[dst[e]], 1);
}

__global__ __launch_bounds__(1024) void scan_block_kernel(const int* __restrict__ cnt,
                                                          int* __restrict__ excl,
                                                          int* __restrict__ bsum, int n) {
    __shared__ int s[1024];
    int i = blockIdx.x * 1024 + threadIdx.x;
    int v = i < n ? cnt[i] : 0;
    s[threadIdx.x] = v;
    __syncthreads();
    for (int off = 1; off < 1024; off <<= 1) {
        int t = threadIdx.x >= off ? s[threadIdx.x - off] : 0;
        __syncthreads();
        s[threadIdx.x] += t;
        __syncthreads();
    }
    if (i < n) excl[i] = s[threadIdx.x] - v;
    if (threadIdx.x == 1023) bsum[blockIdx.x] = s[1023];
}

__global__ void scan_aux_kernel(int* __restrict__ bsum, int nb) {
    if (blockIdx.x == 0 && threadIdx.x == 0) {
        int acc = 0;
        for (int i = 0; i < nb; ++i) { int v = bsum[i]; bsum[i] = acc; acc += v; }
    }
}

__global__ void scan_add_kernel(const int* __restrict__ excl, const int* __restrict__ bsum,
                                int* __restrict__ rowptr, int* __restrict__ fill, int n, int E) {
    int i = blockIdx.x * blockDim.x + threadIdx.x;
    if (i < n) {
        int v = excl[i] + bsum[i >> 10];
        rowptr[i] = v;
        fill[i] = v;
    }
    if (i == 0) rowptr[n] = E;
}

__global__ void scatter_kernel(const int* __restrict__ src, const int* __restrict__ dst, int E,
                               int* __restrict__ fill, int* __restrict__ csrc) {
    int e = blockIdx.x * blockDim.x + threadIdx.x;
    if (e >= E) return;
    int pos = atomicAdd(&fill[dst[e]], 1);
    csrc[pos] = src[e];
}

// ---------------- wave-per-dst fused softmax + aggregation ----------------
// Gather loop: 1-ahead rotating prefetch (one 16B load in flight during the
// consume). SS fully initialized (tail = self row d) so no guards needed.
// MODE 0: bias+ELU -> hi/lo bf16 planes, chunk-swizzled (feeds gemm2)
// MODE 1: bias+ELU -> h3 = h2@W3, as3/ad3 (h2 not stored)

template <int MODE>
__global__ __launch_bounds__(256) void gat_aggr_wave(
    const int* __restrict__ rowptr, const int* __restrict__ csrc,
    const float* __restrict__ a_s, const float* __restrict__ a_d,
    const __half* __restrict__ h16, const float* __restrict__ bias,
    unsigned short* __restrict__ aggH, unsigned short* __restrict__ aggL,
    const float* __restrict__ W3, const float* __restrict__ asrc3,
    const float* __restrict__ adst3, float* __restrict__ h3,
    float* __restrict__ as3, float* __restrict__ ad3, int N) {
    __shared__ float sexs[4][64 * 8];
    __shared__ int ssrcs[4][64];
    int wv = threadIdx.x >> 6, l = threadIdx.x & 63;
    int d = blockIdx.x * 4 + wv;
    if (d >= N) return;
    float* SX = sexs[wv];
    int* SS = ssrcs[wv];
    int beg = rowptr[d], deg = rowptr[d + 1] - beg;
    int hq = l & 7, hmy = l >> 3;
    float adq = a_d[d * 8 + hq];

    // pass 1: per-head max over all edges (+self)
    float m = -INFINITY;
    for (int i = l >> 3; i <= deg; i += 8) {
        int s = (i == deg) ? d : csrc[beg + i];
        float v = a_s[s * 8 + hq] + adq;
        v = v >= 0.f ? v : 0.2f * v;
        m = fmaxf(m, v);
    }
    m = fmaxf(m, __shfl_xor(m, 8));
    m = fmaxf(m, __shfl_xor(m, 16));
    m = fmaxf(m, __shfl_xor(m, 32));

    // pass 2 (chunked): exp -> LDS, denom partials, prefetched feature gather
    float den = 0.f;
    float acc[8] = {};
    for (int c0 = 0; c0 <= deg; c0 += 64) {
        int cnt = min(64, deg + 1 - c0);
        {
            int i = c0 + l;
            SS[l] = (i < deg) ? csrc[beg + i] : d;   // i==deg -> self; i>deg -> safe dummy
        }
        __builtin_amdgcn_wave_barrier();
        for (int i = l >> 3; i < cnt; i += 8) {
            int s = SS[i];
            float v = a_s[s * 8 + hq] + adq;
            v = v >= 0.f ? v : 0.2f * v;
            float ex = __expf(v - m);
            SX[i * 8 + hq] = ex;
            den += ex;
        }
        __builtin_amdgcn_wave_barrier();
        {
            int sj = SS[0];
            uint4 hv = *(const uint4*)(h16 + (size_t)sj * F512 + l * 8);
            for (int j = 0; j < cnt; ++j) {
                int sn = SS[(j + 1) & 63];           // tail slot = dummy self row (valid)
                uint4 nx = *(const uint4*)(h16 + (size_t)sn * F512 + l * 8);
                float ex = SX[j * 8 + hmy];
                const __half2* hp = (const __half2*)&hv;
#pragma unroll
                for (int k = 0; k < 4; ++k) {
                    float2 f = __half22float2(hp[k]);
                    acc[2 * k] += ex * f.x;
                    acc[2 * k + 1] += ex * f.y;
                }
                hv = nx;
            }
        }
        __builtin_amdgcn_wave_barrier();
    }
    den += __shfl_xor(den, 8);
    den += __shfl_xor(den, 16);
    den += __shfl_xor(den, 32);
    float dg = __shfl(den, hmy);
    float inv = 1.f / (dg + 1e-16f);

    int c0c = l * 8;
    float o[8];
#pragma unroll
    for (int k = 0; k < 8; ++k) {
        float t = acc[k] * inv + bias[c0c + k];
        o[k] = t > 0.f ? t : expm1f(t);
    }

    if (MODE == 0) {
        unsigned short hs[8], ls[8];
#pragma unroll
        for (int k = 0; k < 8; ++k) {
            unsigned hi = bf16_rne(o[k]);
            float r = o[k] - __uint_as_float(hi << 16);
            hs[k] = (unsigned short)hi;
            ls[k] = (unsigned short)bf16_rne(r);
        }
        int st = (l >> 2) * 32 + (((l & 3) ^ ((d >> 1) & 3)) << 3);
        *(uint4*)&aggH[(size_t)d * F512 + st] = *(uint4*)hs;
        *(uint4*)&aggL[(size_t)d * F512 + st] = *(uint4*)ls;
    } else {
        float p0 = 0.f, p1 = 0.f, p2 = 0.f;
#pragma unroll
        for (int k = 0; k < 8; ++k) {
            float t = o[k];
            p0 += t * W3[(c0c + k) * 3 + 0];
            p1 += t * W3[(c0c + k) * 3 + 1];
            p2 += t * W3[(c0c + k) * 3 + 2];
        }
#pragma unroll
        for (int off = 1; off < 64; off <<= 1) {
            p0 += __shfl_xor(p0, off);
            p1 += __shfl_xor(p1, off);
            p2 += __shfl_xor(p2, off);
        }
        if (l == 0) {
            h3[(size_t)d * 3 + 0] = p0;
            h3[(size_t)d * 3 + 1] = p1;
            h3[(size_t)d * 3 + 2] = p2;
            as3[d] = p0 * asrc3[0] + p1 * asrc3[1] + p2 * asrc3[2];
            ad3[d] = p0 * adst3[0] + p1 * adst3[1] + p2 * adst3[2];
        }
    }
}

// ---------------- Layer-2 GEMM: hi/lo planes + global_load_lds + fused alpha ----------------
__global__ __launch_bounds__(256) void gemm2_gll(
    const unsigned short* __restrict__ AH, const unsigned short* __restrict__ AL,
    const unsigned short* __restrict__ BH, const unsigned short* __restrict__ BL,
    const float* __restrict__ asrc2, const float* __restrict__ adst2,
    __half* __restrict__ C, float* __restrict__ a_s, float* __restrict__ a_d,
    int M) {
    __shared__ unsigned short AsH[128 * 32], AsL[128 * 32];
    __shared__ unsigned short BsH[128 * 32], BsL[128 * 32];

    int nwg = gridDim.x, o = blockIdx.x;
    int q = nwg >> 3, r = nwg & 7, xcd = o & 7;
    int base = xcd < r ? xcd * (q + 1) : r * (q + 1) + (xcd - r) * q;
    int lg = base + (o >> 3);
    int mb = lg >> 2, nb = lg & 3;

    int tid = threadIdx.x, lane = tid & 63, wv = tid >> 6;
    int wm = wv >> 1, wn = wv & 1;
    int seg = lane >> 4;
    int srow = tid >> 2, sch = tid & 3;

    f32x4 acc[4][4] = {};

    for (int k0 = 0; k0 < F512; k0 += 32) {
#pragma unroll
        for (int u = 0; u < 2; ++u) {
            size_t ga = (size_t)(mb * 128 + srow + u * 64) * F512 + k0 + sch * 8;
            size_t gb = (size_t)(nb * 128 + srow + u * 64) * F512 + k0 + sch * 8;
            int ldst = wv * 512 + u * 2048;
            gll16(AH + ga, &AsH[ldst]);
            gll16(AL + ga, &AsL[ldst]);
            gll16(BH + gb, &BsH[ldst]);
            gll16(BL + gb, &BsL[ldst]);
        }
        __syncthreads();

        bf16x8 aH[4], aL[4], bH[4], bL[4];
#pragma unroll
        for (int mi = 0; mi < 4; ++mi) {
            int arow = wm * 64 + mi * 16 + (lane & 15);
            int aoff = arow * 32 + ((seg ^ ((arow >> 1) & 3)) << 3);
            aH[mi] = __builtin_bit_cast(bf16x8, *(const u16x8*)&AsH[aoff]);
            aL[mi] = __builtin_bit_cast(bf16x8, *(const u16x8*)&AsL[aoff]);
        }
#pragma unroll
        for (int ni = 0; ni < 4; ++ni) {
            int brow = wn * 64 + ni * 16 + (lane & 15);
            int boff = brow * 32 + ((seg ^ ((brow >> 1) & 3)) << 3);
            bH[ni] = __builtin_bit_cast(bf16x8, *(const u16x8*)&BsH[boff]);
            bL[ni] = __builtin_bit_cast(bf16x8, *(const u16x8*)&BsL[boff]);
        }
#pragma unroll
        for (int mi = 0; mi < 4; ++mi)
#pragma unroll
            for (int ni = 0; ni < 4; ++ni) {
                acc[mi][ni] = __builtin_amdgcn_mfma_f32_16x16x32_bf16(aH[mi], bH[ni], acc[mi][ni], 0, 0, 0);
                acc[mi][ni] = __builtin_amdgcn_mfma_f32_16x16x32_bf16(aH[mi], bL[ni], acc[mi][ni], 0, 0, 0);
                acc[mi][ni] = __builtin_amdgcn_mfma_f32_16x16x32_bf16(aL[mi], bH[ni], acc[mi][ni], 0, 0, 0);
            }
        __syncthreads();
    }

    // C (fp16 h2pre) write
#pragma unroll
    for (int mi = 0; mi < 4; ++mi) {
#pragma unroll
        for (int ni = 0; ni < 4; ++ni) {
            int rbase = mb * 128 + wm * 64 + mi * 16 + (lane >> 4) * 4;
            int c = nb * 128 + wn * 64 + ni * 16 + (lane & 15);
#pragma unroll
            for (int i = 0; i < 4; ++i) {
                int row = rbase + i;
                if (row < M) C[(size_t)row * F512 + c] = __float2half_rn(acc[mi][ni][i]);
            }
        }
    }

    // fused alpha: this wave's 64 cols == head (nb*2+wn)
    int head = nb * 2 + wn;
    float av[4], dv[4];
#pragma unroll
    for (int ni = 0; ni < 4; ++ni) {
        int cw = ni * 16 + (lane & 15);
        av[ni] = asrc2[head * 64 + cw];
        dv[ni] = adst2[head * 64 + cw];
    }
#pragma unroll
    for (int mi = 0; mi < 4; ++mi)
#pragma unroll
        for (int i = 0; i < 4; ++i) {
            float sp = 0.f, dp = 0.f;
#pragma unroll
            for (int ni = 0; ni < 4; ++ni) {
                sp += acc[mi][ni][i] * av[ni];
                dp += acc[mi][ni][i] * dv[ni];
            }
            sp += __shfl_xor(sp, 1); dp += __shfl_xor(dp, 1);
            sp += __shfl_xor(sp, 2); dp += __shfl_xor(dp, 2);
            sp += __shfl_xor(sp, 4); dp += __shfl_xor(dp, 4);
            sp += __shfl_xor(sp, 8); dp += __shfl_xor(dp, 8);
            if ((lane & 15) == 0) {
                int row = mb * 128 + wm * 64 + mi * 16 + (lane >> 4) * 4 + i;
                if (row < M) { a_s[row * 8 + head] = sp; a_d[row * 8 + head] = dp; }
            }
        }
}

// ---------------- layer-3 aggregation ----------------
__global__ __launch_bounds__(256) void gat_aggr3_fused(
    const int* __restrict__ rowptr, const int* __restrict__ csrc,
    const float* __restrict__ a_s, const float* __restrict__ a_d,
    const float* __restrict__ h3, const float* __restrict__ b3,
    float* __restrict__ out, int N) {
    int w = (blockIdx.x * blockDim.x + threadIdx.x) >> 6;
    int lane = threadIdx.x & 63;
    if (w >= N) return;
    int d = w;
    int beg = rowptr[d], deg = rowptr[d + 1] - beg;
    float ad = a_d[d];
    float m = -INFINITY;
    for (int i = lane; i <= deg; i += 64) {
        int s = (i == deg) ? d : csrc[beg + i];
        float v = a_s[s] + ad;
        v = v >= 0.f ? v : 0.2f * v;
        m = fmaxf(m, v);
    }
    for (int off = 32; off; off >>= 1) m = fmaxf(m, __shfl_xor(m, off));
    float den = 0.f, c0 = 0.f, c1 = 0.f, c2 = 0.f;
    for (int i = lane; i <= deg; i += 64) {
        int s = (i == deg) ? d : csrc[beg + i];
        float v = a_s[s] + ad;
        v = v >= 0.f ? v : 0.2f * v;
        float ex = __expf(v - m);
        den += ex;
        c0 += ex * h3[(size_t)s * 3 + 0];
        c1 += ex * h3[(size_t)s * 3 + 1];
        c2 += ex * h3[(size_t)s * 3 + 2];
    }
    for (int off = 32; off; off >>= 1) {
        den += __shfl_xor(den, off);
        c0 += __shfl_xor(c0, off);
        c1 += __shfl_xor(c1, off);
        c2 += __shfl_xor(c2, off);
    }
    if (lane == 0) {
        float inv = 1.f / (den + 1e-16f);
        out[(size_t)d * 3 + 0] = c0 * inv + b3[0];
        out[(size_t)d * 3 + 1] = c1 * inv + b3[1];
        out[(size_t)d * 3 + 2] = c2 * inv + b3[2];
    }
}

static inline int cdiv(long long a, long long b) { return (int)((a + b - 1) / b); }
static inline size_t rup(size_t v) { return (v + 255) & ~(size_t)255; }

extern "C" void kernel_launch(void* const* d_in, const int* in_sizes, int n_in,
                              void* d_out, int out_size, void* d_ws, size_t ws_size,
                              hipStream_t stream) {
    const int N = in_sizes[0] / 12;
    const int E = in_sizes[1] / 2;
    const float* x     = (const float*)d_in[0];
    const int*   ei    = (const int*)d_in[1];
    const float* W1    = (const float*)d_in[2];
    const float* asrc1 = (const float*)d_in[3];
    const float* adst1 = (const float*)d_in[4];
    const float* b1    = (const float*)d_in[5];
    const float* W2    = (const float*)d_in[6];
    const float* asrc2 = (const float*)d_in[7];
    const float* adst2 = (const float*)d_in[8];
    const float* b2    = (const float*)d_in[9];
    const float* W3    = (const float*)d_in[10];
    const float* asrc3 = (const float*)d_in[11];
    const float* adst3 = (const float*)d_in[12];
    const float* b3    = (const float*)d_in[13];

    const int* srcv = ei;
    const int* dstv = ei + E;
    float* out = (float*)d_out;

    const int Mpad = cdiv(N, 128) * 128;
    char* p = (char*)d_ws;
    __half*         h16  = (__half*)p;         p += rup((size_t)N * F512 * 2);
    unsigned short* aggH = (unsigned short*)p; p += rup((size_t)Mpad * F512 * 2);
    unsigned short* aggL = (unsigned short*)p; p += rup((size_t)Mpad * F512 * 2);
    float* a_s    = (float*)p;  p += rup((size_t)Mpad * HEADS * 4);
    float* a_d    = (float*)p;  p += rup((size_t)Mpad * HEADS * 4);
    float* h3     = (float*)p;  p += rup((size_t)N * 3 * 4);
    float* as3    = (float*)p;  p += rup((size_t)N * 4);
    float* ad3    = (float*)p;  p += rup((size_t)N * 4);
    int*   cnt    = (int*)p;    p += rup((size_t)N * 4);
    int*   excl   = (int*)p;    p += rup((size_t)N * 4);
    int*   rowptr = (int*)p;    p += rup((size_t)(N + 1) * 4);
    int*   fill   = (int*)p;    p += rup((size_t)N * 4);
    int*   bsum   = (int*)p;    p += rup(4096);
    int*   csrc   = (int*)p;    p += rup((size_t)E * 4);
    unsigned short* BTH = (unsigned short*)p; p += rup((size_t)F512 * F512 * 2);
    unsigned short* BTL = (unsigned short*)p; p += rup((size_t)F512 * F512 * 2);

    const int nb = cdiv(N, 1024);

    // ---- CSR build + W2 plane conversion ----
    hipMemsetAsync(cnt, 0, (size_t)N * 4, stream);
    hist_kernel<<<cdiv(E, 256), 256, 0, stream>>>(dstv, E, cnt);
    scan_block_kernel<<<nb, 1024, 0, stream>>>(cnt, excl, bsum, N);
    scan_aux_kernel<<<1, 64, 0, stream>>>(bsum, nb);
    scan_add_kernel<<<cdiv(N + 1, 256), 256, 0, stream>>>(excl, bsum, rowptr, fill, N, E);
    scatter_kernel<<<cdiv(E, 256), 256, 0, stream>>>(srcv, dstv, E, fill, csrc);
    convW2p<<<cdiv(F512 * 64, 256), 256, 0, stream>>>(W2, BTH, BTL);

    // ----------------- Layer 1 -----------------
    gemm1_fused<<<cdiv((long long)N * 64, 256), 256, 0, stream>>>(
        x, W1, asrc1, adst1, h16, a_s, a_d, N);
    gat_aggr_wave<0><<<cdiv(N, 4), 256, 0, stream>>>(
        rowptr, csrc, a_s, a_d, h16, b1, aggH, aggL,
        nullptr, nullptr, nullptr, nullptr, nullptr, nullptr, N);

    // ----------------- Layer 2 -----------------
    gemm2_gll<<<(Mpad / 128) * 4, 256, 0, stream>>>(
        aggH, aggL, BTH, BTL, asrc2, adst2, h16, a_s, a_d, N);
    gat_aggr_wave<1><<<cdiv(N, 4), 256, 0, stream>>>(
        rowptr, csrc, a_s, a_d, h16, b2, nullptr, nullptr,
        W3, asrc3, adst3, h3, as3, ad3, N);

    // ----------------- Layer 3 -----------------
    gat_aggr3_fused<<<cdiv((long long)N, 4), 256, 0, stream>>>(
        rowptr, csrc, as3, ad3, h3, b3, out, N);
}